// Round 3
// baseline (158.742 us; speedup 1.0000x reference)
//
#include <hip/hip_runtime.h>
#include <math.h>

// Problem constants (B=4, S=2048, E=1024, A=64)
#define BATCH 4
#define SLEN  2048
#define EMB   1024
#define AH    64

typedef __attribute__((ext_vector_type(8))) short bf16x8;
typedef __attribute__((ext_vector_type(4))) float f32x4;

__device__ __forceinline__ short f2bf(float x) {
  union { float f; unsigned u; } v; v.f = x;
  unsigned r = v.u + 0x7fffu + ((v.u >> 16) & 1u);
  return (short)(r >> 16);
}
__device__ __forceinline__ float bf2f(short h) {
  union { unsigned u; float f; } v; v.u = ((unsigned)(unsigned short)h) << 16;
  return v.f;
}

// ---------------------------------------------------------------------------
// Kernel 0: pack Wk [64,1024] fp32 into MFMA B-fragment order, split bf16.
// Bpk layout: [h(2)][kc(32)][nt(4)][lane(64)][j(8)] bf16.
// ---------------------------------------------------------------------------
__global__ __launch_bounds__(256) void prep_wk_kernel(const float* __restrict__ Wk,
                                                      short* __restrict__ Bpk) {
  int tg = blockIdx.x * 256 + threadIdx.x;  // 8192 = 32kc * 4nt * 64lane
  int kc = tg >> 8, rem = tg & 255, nt = rem >> 6, lane = rem & 63;
  int n = nt * 16 + (lane & 15);
  int k = kc * 32 + (lane >> 4) * 8;
  const float* src = Wk + (size_t)n * EMB + k;
  float4 a0 = *(const float4*)src;
  float4 a1 = *(const float4*)(src + 4);
  float x[8] = {a0.x, a0.y, a0.z, a0.w, a1.x, a1.y, a1.z, a1.w};
  bf16x8 hi, lo;
#pragma unroll
  for (int j = 0; j < 8; ++j) {
    short h = f2bf(x[j]);
    hi[j] = h;
    lo[j] = f2bf(x[j] - bf2f(h));
  }
  short* dst = Bpk + ((size_t)(kc * 4 + nt) * 64 + lane) * 8;
  *(bf16x8*)dst = hi;
  *(bf16x8*)(dst + 65536) = lo;
}

// ---------------------------------------------------------------------------
// Kernel 1: K = emb @ Wk^T, split-E 2-way for 2x wave count (4 waves/SIMD).
// grid 1024: block (row_tile = bx>>1, ehalf = bx&1); fp32 partials out.
// ---------------------------------------------------------------------------
__global__ __launch_bounds__(256) void gemm_k_kernel(const float* __restrict__ emb,
                                                     const short* __restrict__ Bpk,
                                                     float* __restrict__ Kpart) {
  const int t = threadIdx.x;
  const int l = t & 63, lm = l & 15, quad = l >> 4;
  const int nt = t >> 6;
  const int row0 = (blockIdx.x >> 1) * 16;
  const int eh = blockIdx.x & 1;

  f32x4 acc = {0.f, 0.f, 0.f, 0.f};
  const float* arow = emb + (size_t)(row0 + lm) * EMB + eh * 512 + quad * 8;

#pragma unroll 4
  for (int kc = 0; kc < 16; ++kc) {
    float4 a0 = *(const float4*)(arow + kc * 32);
    float4 a1 = *(const float4*)(arow + kc * 32 + 4);
    float x[8] = {a0.x, a0.y, a0.z, a0.w, a1.x, a1.y, a1.z, a1.w};
    bf16x8 ahi, alo;
#pragma unroll
    for (int j = 0; j < 8; ++j) {
      short h = f2bf(x[j]);
      ahi[j] = h;
      alo[j] = f2bf(x[j] - bf2f(h));
    }
    const short* bp = Bpk + ((size_t)((eh * 16 + kc) * 4 + nt) * 64 + l) * 8;
    bf16x8 bhi = *(const bf16x8*)bp;
    bf16x8 blo = *(const bf16x8*)(bp + 65536);
    acc = __builtin_amdgcn_mfma_f32_16x16x32_bf16(ahi, bhi, acc, 0, 0, 0);
    acc = __builtin_amdgcn_mfma_f32_16x16x32_bf16(ahi, blo, acc, 0, 0, 0);
    acc = __builtin_amdgcn_mfma_f32_16x16x32_bf16(alo, bhi, acc, 0, 0, 0);
  }

  float* Kp = Kpart + (size_t)eh * 524288;
#pragma unroll
  for (int r = 0; r < 4; ++r)
    Kp[(size_t)(row0 + quad * 4 + r) * AH + nt * 16 + lm] = acc[r];
}

// ---------------------------------------------------------------------------
// Kernel 1b: reduce the two E-half partials, convert to split bf16, and
// produce Khi/Klo (natural) + KThi (transposed, via LDS). grid 512.
// ---------------------------------------------------------------------------
__global__ __launch_bounds__(256) void kred_kernel(const float* __restrict__ Kpart,
                                                   short* __restrict__ Khi,
                                                   short* __restrict__ Klo,
                                                   short* __restrict__ KThi) {
  __shared__ short ldsT[64][20];
  const int t = threadIdx.x;
  const int row0 = blockIdx.x * 16;
  const int s_l = t >> 4, a0 = (t & 15) * 4;
  size_t idx = (size_t)(row0 + s_l) * AH + a0;
  float4 p0 = *(const float4*)&Kpart[idx];
  float4 p1 = *(const float4*)&Kpart[524288 + idx];
  float v[4] = {p0.x + p1.x, p0.y + p1.y, p0.z + p1.z, p0.w + p1.w};
  short hs[4], ls[4];
#pragma unroll
  for (int j = 0; j < 4; ++j) {
    hs[j] = f2bf(v[j]);
    ls[j] = f2bf(v[j] - bf2f(hs[j]));
    ldsT[a0 + j][s_l] = hs[j];
  }
  *(short4*)&Khi[idx] = make_short4(hs[0], hs[1], hs[2], hs[3]);
  *(short4*)&Klo[idx] = make_short4(ls[0], ls[1], ls[2], ls[3]);
  __syncthreads();
  const int a = t & 63, sg = t >> 6;
  const int b = row0 >> 11, s0 = row0 & 2047;
  short4 tv = *(const short4*)&ldsT[a][sg * 4];
  *(short4*)&KThi[((size_t)b * AH + a) * SLEN + s0 + sg * 4] = tv;
}

// ---------------------------------------------------------------------------
// Kernel 2: flash partials, ONE k-tile per block (max parallelism, no
// loop-carried chain, single-pass softmax). grid (32 kt, 32 qt, 4 b).
// Partial slot = b*528 + qt(qt+1)/2 + kt (compact triangular).
// m/l laid out [b][qt][row(64)][kt(32)] so merge lanes coalesce.
// ---------------------------------------------------------------------------
__global__ __launch_bounds__(256, 3) void flash_partial_kernel(const short* __restrict__ Khi,
                                                               const short* __restrict__ Klo,
                                                               const short* __restrict__ KThi,
                                                               float* __restrict__ Opart,
                                                               float* __restrict__ mpart,
                                                               float* __restrict__ lpart) {
  const int kt = blockIdx.x, qt = blockIdx.y, b = blockIdx.z;
  if (kt > qt) return;

  __shared__ short Plds[4][16][88];
  const int t = threadIdx.x;
  const int w = t >> 6, l = t & 63, lm = l & 15, quad = l >> 4;
  const int qr0 = qt * 64 + w * 16, k0 = kt * 64;

  // Q fragments (A-operand), 16B/lane contiguous
  const size_t qbase = ((size_t)b * SLEN + qr0 + lm) * AH + quad * 8;
  const bf16x8 qh0 = *(const bf16x8*)(Khi + qbase);
  const bf16x8 qh1 = *(const bf16x8*)(Khi + qbase + 32);
  const bf16x8 ql0 = *(const bf16x8*)(Klo + qbase);
  const bf16x8 ql1 = *(const bf16x8*)(Klo + qbase + 32);

  // S = Q K^T (split bf16: hh + hl + lh), all K loads independent
  f32x4 sc[4];
#pragma unroll
  for (int nt = 0; nt < 4; ++nt) {
    const size_t kb = ((size_t)b * SLEN + k0 + nt * 16 + lm) * AH + quad * 8;
    bf16x8 bh0 = *(const bf16x8*)(Khi + kb);
    bf16x8 bl0 = *(const bf16x8*)(Klo + kb);
    bf16x8 bh1 = *(const bf16x8*)(Khi + kb + 32);
    bf16x8 bl1 = *(const bf16x8*)(Klo + kb + 32);
    f32x4 s = {0.f, 0.f, 0.f, 0.f};
    s = __builtin_amdgcn_mfma_f32_16x16x32_bf16(qh0, bh0, s, 0, 0, 0);
    s = __builtin_amdgcn_mfma_f32_16x16x32_bf16(qh0, bl0, s, 0, 0, 0);
    s = __builtin_amdgcn_mfma_f32_16x16x32_bf16(ql0, bh0, s, 0, 0, 0);
    s = __builtin_amdgcn_mfma_f32_16x16x32_bf16(qh1, bh1, s, 0, 0, 0);
    s = __builtin_amdgcn_mfma_f32_16x16x32_bf16(qh1, bl1, s, 0, 0, 0);
    s = __builtin_amdgcn_mfma_f32_16x16x32_bf16(ql1, bh1, s, 0, 0, 0);
    sc[nt] = s;
  }

  // V loads issued here: latency overlaps the softmax below
  bf16x8 vf[2][4];
#pragma unroll
  for (int kc2 = 0; kc2 < 2; ++kc2)
#pragma unroll
    for (int nt = 0; nt < 4; ++nt)
      vf[kc2][nt] = *(const bf16x8*)(KThi + ((size_t)b * AH + nt * 16 + lm) * SLEN +
                                     k0 + kc2 * 32 + quad * 8);

  // mask + single-pass softmax (C layout: row=quad*4+r, col=nt*16+lm)
  float sv[4][4];
  float rm[4] = {-INFINITY, -INFINITY, -INFINITY, -INFINITY};
#pragma unroll
  for (int nt = 0; nt < 4; ++nt) {
    const int col = k0 + nt * 16 + lm;
#pragma unroll
    for (int r = 0; r < 4; ++r) {
      const int row = qr0 + quad * 4 + r;
      float v = sc[nt][r] * 0.125f;
      if (col > row || v == 0.0f) v = -INFINITY;
      sv[nt][r] = v;
      rm[r] = fmaxf(rm[r], v);
    }
  }
  float m_i[4], l_i[4];
#pragma unroll
  for (int r = 0; r < 4; ++r) {
    for (int off = 1; off < 16; off <<= 1) rm[r] = fmaxf(rm[r], __shfl_xor(rm[r], off, 16));
    m_i[r] = rm[r];
  }
  float pv[4][4], rs[4] = {0.f, 0.f, 0.f, 0.f};
#pragma unroll
  for (int nt = 0; nt < 4; ++nt)
#pragma unroll
    for (int r = 0; r < 4; ++r) {
      float p = (sv[nt][r] == -INFINITY) ? 0.f : __expf(sv[nt][r] - m_i[r]);
      pv[nt][r] = p;
      rs[r] += p;
    }
#pragma unroll
  for (int r = 0; r < 4; ++r) {
    for (int off = 1; off < 16; off <<= 1) rs[r] += __shfl_xor(rs[r], off, 16);
    l_i[r] = rs[r];
  }

  // P -> LDS (C layout -> A-operand layout), per-wave private, wave-sync only
#pragma unroll
  for (int nt = 0; nt < 4; ++nt)
#pragma unroll
    for (int r = 0; r < 4; ++r)
      Plds[w][quad * 4 + r][nt * 16 + lm] = f2bf(pv[nt][r]);

  // O = P V
  f32x4 o[4] = {{0.f,0.f,0.f,0.f},{0.f,0.f,0.f,0.f},{0.f,0.f,0.f,0.f},{0.f,0.f,0.f,0.f}};
#pragma unroll
  for (int kc2 = 0; kc2 < 2; ++kc2) {
    bf16x8 pf = *(const bf16x8*)&Plds[w][lm][kc2 * 32 + quad * 8];
#pragma unroll
    for (int nt = 0; nt < 4; ++nt)
      o[nt] = __builtin_amdgcn_mfma_f32_16x16x32_bf16(pf, vf[kc2][nt], o[nt], 0, 0, 0);
  }

  // write partials (compact triangular slot)
  const size_t slot = (size_t)b * 528 + ((qt * (qt + 1)) >> 1) + kt;
  float* Ob = Opart + slot * 4096;
#pragma unroll
  for (int nt = 0; nt < 4; ++nt)
#pragma unroll
    for (int r = 0; r < 4; ++r)
      Ob[(size_t)(w * 16 + quad * 4 + r) * AH + nt * 16 + lm] = o[nt][r];
  if (lm == 0) {
#pragma unroll
    for (int r = 0; r < 4; ++r) {
      size_t mi = ((size_t)(b * 32 + qt) * 64 + w * 16 + quad * 4 + r) * 32 + kt;
      mpart[mi] = m_i[r];
      lpart[mi] = l_i[r];
    }
  }
}

// ---------------------------------------------------------------------------
// Kernel 3: merge. ONE WAVE PER OUTPUT ROW (8192 waves = 8/SIMD).
// Lane c loads m_c/l_c (coalesced 128B), wave-reduce M and L, weights to
// LDS, then lane a accumulates sum_c w_c * Opart[c][row][a], 4-way unrolled.
// ---------------------------------------------------------------------------
__global__ __launch_bounds__(256) void merge_kernel(const float* __restrict__ Opart,
                                                    const float* __restrict__ mpart,
                                                    const float* __restrict__ lpart,
                                                    float* __restrict__ out) {
  __shared__ float wbuf[4][32];
  const int t = threadIdx.x, w = t >> 6, l = t & 63;
  const int row = blockIdx.x * 4 + w;
  const int b = row >> 11, s = row & 2047, qt = s >> 6, r = s & 63;
  const int nch = qt + 1;

  const size_t mbase = ((size_t)(b * 32 + qt) * 64 + r) * 32;
  float ml = (l < nch) ? mpart[mbase + l] : -INFINITY;
  float M = ml;
  for (int off = 1; off < 64; off <<= 1) M = fmaxf(M, __shfl_xor(M, off));
  float wgt = (l < nch && ml != -INFINITY) ? __expf(ml - M) : 0.f;
  float lw = (l < nch) ? lpart[mbase + l] * wgt : 0.f;
  float L = lw;
  for (int off = 1; off < 64; off <<= 1) L += __shfl_xor(L, off);
  if (l < 32) wbuf[w][l] = wgt;  // per-wave buffer, wave-sync only

  const size_t obase = ((size_t)b * 528 + ((qt * (qt + 1)) >> 1)) * 4096 + (size_t)r * AH + l;
  float a0 = 0.f, a1 = 0.f, a2 = 0.f, a3 = 0.f;
  int c = 0;
  for (; c + 3 < nch; c += 4) {
    a0 += wbuf[w][c]     * Opart[obase + (size_t)c * 4096];
    a1 += wbuf[w][c + 1] * Opart[obase + (size_t)(c + 1) * 4096];
    a2 += wbuf[w][c + 2] * Opart[obase + (size_t)(c + 2) * 4096];
    a3 += wbuf[w][c + 3] * Opart[obase + (size_t)(c + 3) * 4096];
  }
  for (; c < nch; ++c) a0 += wbuf[w][c] * Opart[obase + (size_t)c * 4096];
  float acc = (a0 + a1) + (a2 + a3);
  out[(size_t)row * AH + l] = acc / L;
}

// ---------------------------------------------------------------------------
// Workspace layout (bytes):
//   Bpk    [0,        262144)
//   Kpart  [262144,   4456448)    2 x 512K fp32
//   Khi    [4456448,  5505024)
//   Klo    [5505024,  6553600)
//   KThi   [6553600,  7602176)
//   Opart  [7602176,  42205184)   4*528 slots x 4096 fp32 (34.6 MB)
//   mpart  [42205184, 43253760)
//   lpart  [43253760, 44302336)   total ~44.3 MB
// ---------------------------------------------------------------------------
extern "C" void kernel_launch(void* const* d_in, const int* in_sizes, int n_in,
                              void* d_out, int out_size, void* d_ws, size_t ws_size,
                              hipStream_t stream) {
  const float* emb = (const float*)d_in[0];
  const float* Wk  = (const float*)d_in[1];
  float* out = (float*)d_out;
  char* ws = (char*)d_ws;

  short* Bpk   = (short*)(ws);
  float* Kpart = (float*)(ws + 262144);
  short* Khi   = (short*)(ws + 4456448);
  short* Klo   = (short*)(ws + 5505024);
  short* KThi  = (short*)(ws + 6553600);
  float* Opart = (float*)(ws + 7602176);
  float* mpart = (float*)(ws + 42205184);
  float* lpart = (float*)(ws + 43253760);

  prep_wk_kernel<<<dim3(32), dim3(256), 0, stream>>>(Wk, Bpk);
  gemm_k_kernel<<<dim3(1024), dim3(256), 0, stream>>>(emb, Bpk, Kpart);
  kred_kernel<<<dim3(512), dim3(256), 0, stream>>>(Kpart, Khi, Klo, KThi);
  flash_partial_kernel<<<dim3(32, 32, 4), dim3(256), 0, stream>>>(Khi, Klo, KThi, Opart, mpart, lpart);
  merge_kernel<<<dim3(2048), dim3(256), 0, stream>>>(Opart, mpart, lpart, out);
}

// Round 4
// 144.755 us; speedup vs baseline: 1.0966x; 1.0966x over previous
//
#include <hip/hip_runtime.h>
#include <math.h>

// Problem constants (B=4, S=2048, E=1024, A=64)
#define BATCH 4
#define SLEN  2048
#define EMB   1024
#define AH    64

typedef __attribute__((ext_vector_type(8))) short bf16x8;
typedef __attribute__((ext_vector_type(4))) float f32x4;

__device__ __forceinline__ short f2bf(float x) {  // RNE
  union { float f; unsigned u; } v; v.f = x;
  unsigned r = v.u + 0x7fffu + ((v.u >> 16) & 1u);
  return (short)(r >> 16);
}
__device__ __forceinline__ float bf2f(short h) {
  union { unsigned u; float f; } v; v.u = ((unsigned)(unsigned short)h) << 16;
  return v.f;
}

// Truncate-split 8 fp32 -> bf16 hi (high16) + bf16 lo (trunc of residual).
// hi via v_perm (1 op / 2 elems); lo = x - bf2f(hi) then perm-pack.
__device__ __forceinline__ void split_trunc(float4 a0, float4 a1, bf16x8& hi, bf16x8& lo) {
  unsigned c[8] = {__float_as_uint(a0.x), __float_as_uint(a0.y), __float_as_uint(a0.z),
                   __float_as_uint(a0.w), __float_as_uint(a1.x), __float_as_uint(a1.y),
                   __float_as_uint(a1.z), __float_as_uint(a1.w)};
  union { bf16x8 v; unsigned d[4]; } H, L;
  H.d[0] = __builtin_amdgcn_perm(c[1], c[0], 0x07060302u);
  H.d[1] = __builtin_amdgcn_perm(c[3], c[2], 0x07060302u);
  H.d[2] = __builtin_amdgcn_perm(c[5], c[4], 0x07060302u);
  H.d[3] = __builtin_amdgcn_perm(c[7], c[6], 0x07060302u);
  unsigned e[8];
#pragma unroll
  for (int j = 0; j < 8; ++j)
    e[j] = __float_as_uint(__uint_as_float(c[j]) - __uint_as_float(c[j] & 0xffff0000u));
  L.d[0] = __builtin_amdgcn_perm(e[1], e[0], 0x07060302u);
  L.d[1] = __builtin_amdgcn_perm(e[3], e[2], 0x07060302u);
  L.d[2] = __builtin_amdgcn_perm(e[5], e[4], 0x07060302u);
  L.d[3] = __builtin_amdgcn_perm(e[7], e[6], 0x07060302u);
  hi = H.v; lo = L.v;
}

// Triangular chunk-slot offset: off(qt) = sum_{q<qt} (q/2 + 1)
__device__ __forceinline__ int slot_off(int qt) {
  return (qt == 0) ? 0 : qt + (((qt - 1) * (qt - 1)) >> 2);
}

// ---------------------------------------------------------------------------
// Kernel 0: pack Wk [64,1024] fp32 into MFMA B-fragment order, split bf16.
// ---------------------------------------------------------------------------
__global__ __launch_bounds__(256) void prep_wk_kernel(const float* __restrict__ Wk,
                                                      short* __restrict__ Bpk) {
  int tg = blockIdx.x * 256 + threadIdx.x;  // 8192 = 32kc * 4nt * 64lane
  int kc = tg >> 8, rem = tg & 255, nt = rem >> 6, lane = rem & 63;
  int n = nt * 16 + (lane & 15);
  int k = kc * 32 + (lane >> 4) * 8;
  const float* src = Wk + (size_t)n * EMB + k;
  float4 a0 = *(const float4*)src;
  float4 a1 = *(const float4*)(src + 4);
  bf16x8 hi, lo;
  split_trunc(a0, a1, hi, lo);
  short* dst = Bpk + ((size_t)(kc * 4 + nt) * 64 + lane) * 8;
  *(bf16x8*)dst = hi;
  *(bf16x8*)(dst + 65536) = lo;
}

// ---------------------------------------------------------------------------
// Kernel 1: K = emb @ Wk^T via split-bf16 MFMA (hh+hl+lh). 512 blocks.
// No LDS, no barriers. Outputs Khi/Klo (natural) + KThi (transposed).
// ---------------------------------------------------------------------------
__global__ __launch_bounds__(256) void gemm_k_kernel(const float* __restrict__ emb,
                                                     const short* __restrict__ Bpk,
                                                     short* __restrict__ Khi,
                                                     short* __restrict__ Klo,
                                                     short* __restrict__ KThi) {
  const int t = threadIdx.x;
  const int l = t & 63, lm = l & 15, quad = l >> 4;
  const int nt = t >> 6;
  const int row0 = blockIdx.x * 16;

  f32x4 acc = {0.f, 0.f, 0.f, 0.f};
  const float* arow = emb + (size_t)(row0 + lm) * EMB + quad * 8;

#pragma unroll 8
  for (int kc = 0; kc < 32; ++kc) {
    float4 a0 = *(const float4*)(arow + kc * 32);
    float4 a1 = *(const float4*)(arow + kc * 32 + 4);
    bf16x8 ahi, alo;
    split_trunc(a0, a1, ahi, alo);
    const short* bp = Bpk + ((size_t)(kc * 4 + nt) * 64 + l) * 8;
    bf16x8 bhi = *(const bf16x8*)bp;
    bf16x8 blo = *(const bf16x8*)(bp + 65536);
    acc = __builtin_amdgcn_mfma_f32_16x16x32_bf16(ahi, bhi, acc, 0, 0, 0);
    acc = __builtin_amdgcn_mfma_f32_16x16x32_bf16(ahi, blo, acc, 0, 0, 0);
    acc = __builtin_amdgcn_mfma_f32_16x16x32_bf16(alo, bhi, acc, 0, 0, 0);
  }

  // epilogue: C layout col=lm, row=quad*4+r  (RNE split for K outputs)
  const int b = row0 >> 11, s0 = row0 & 2047;
  short hi4[4];
#pragma unroll
  for (int r = 0; r < 4; ++r) {
    float v = acc[r];
    short h = f2bf(v);
    short lo = f2bf(v - bf2f(h));
    hi4[r] = h;
    size_t idx = (size_t)(row0 + quad * 4 + r) * AH + nt * 16 + lm;
    Khi[idx] = h;
    Klo[idx] = lo;
  }
  size_t kt_idx = ((size_t)b * AH + nt * 16 + lm) * SLEN + s0 + quad * 4;
  *(short4*)&KThi[kt_idx] = make_short4(hi4[0], hi4[1], hi4[2], hi4[3]);
}

// ---------------------------------------------------------------------------
// Kernel 2: flash partials, Bk=128 single-shot (no online-softmax loop).
// grid (16 chunks, 32 qt, 4 b) x 256; wave = 16 q-rows, fully private.
// Opart in bf16 (8 KB/block contiguous); (m,l) as float2 (512B/block).
// ---------------------------------------------------------------------------
__global__ __launch_bounds__(256) void flash_kernel(const short* __restrict__ Khi,
                                                    const short* __restrict__ Klo,
                                                    const short* __restrict__ KThi,
                                                    short* __restrict__ OpartH,
                                                    float2* __restrict__ mlpart) {
  const int chunk = blockIdx.x, qt = blockIdx.y, b = blockIdx.z;
  if (2 * chunk > qt) return;

  __shared__ short Plds[4][16][136];  // per-wave private; row stride 272B (16B-aligned)
  const int t = threadIdx.x;
  const int w = t >> 6, l = t & 63, lm = l & 15, quad = l >> 4;
  const int qr0 = qt * 64 + w * 16, k0 = chunk * 128;

  // Q fragments (A-operand), 16B/lane contiguous
  const size_t qbase = ((size_t)b * SLEN + qr0 + lm) * AH + quad * 8;
  const bf16x8 qh0 = *(const bf16x8*)(Khi + qbase);
  const bf16x8 qh1 = *(const bf16x8*)(Khi + qbase + 32);
  const bf16x8 ql0 = *(const bf16x8*)(Klo + qbase);
  const bf16x8 ql1 = *(const bf16x8*)(Klo + qbase + 32);

  // S = Q K^T over 128 keys: 8 independent col-groups of 16 (g*16+lm)
  f32x4 sc[8];
#pragma unroll
  for (int g = 0; g < 8; ++g) {
    const size_t kb = ((size_t)b * SLEN + k0 + g * 16 + lm) * AH + quad * 8;
    bf16x8 bh0 = *(const bf16x8*)(Khi + kb);
    bf16x8 bl0 = *(const bf16x8*)(Klo + kb);
    bf16x8 bh1 = *(const bf16x8*)(Khi + kb + 32);
    bf16x8 bl1 = *(const bf16x8*)(Klo + kb + 32);
    f32x4 s = {0.f, 0.f, 0.f, 0.f};
    s = __builtin_amdgcn_mfma_f32_16x16x32_bf16(qh0, bh0, s, 0, 0, 0);
    s = __builtin_amdgcn_mfma_f32_16x16x32_bf16(qh0, bl0, s, 0, 0, 0);
    s = __builtin_amdgcn_mfma_f32_16x16x32_bf16(ql0, bh0, s, 0, 0, 0);
    s = __builtin_amdgcn_mfma_f32_16x16x32_bf16(qh1, bh1, s, 0, 0, 0);
    s = __builtin_amdgcn_mfma_f32_16x16x32_bf16(qh1, bl1, s, 0, 0, 0);
    s = __builtin_amdgcn_mfma_f32_16x16x32_bf16(ql1, bh1, s, 0, 0, 0);
    sc[g] = s;
  }

  // prefetch V (first 64 keys) — latency hidden under softmax
  bf16x8 vfA[2][4];
#pragma unroll
  for (int kc2 = 0; kc2 < 2; ++kc2)
#pragma unroll
    for (int nt = 0; nt < 4; ++nt)
      vfA[kc2][nt] = *(const bf16x8*)(KThi + ((size_t)b * AH + nt * 16 + lm) * SLEN +
                                      k0 + kc2 * 32 + quad * 8);

  // mask + single-pass softmax over all 128 cols (C layout: row=quad*4+r, col=g*16+lm)
  float rm[4] = {-INFINITY, -INFINITY, -INFINITY, -INFINITY};
#pragma unroll
  for (int g = 0; g < 8; ++g) {
    const int col = k0 + g * 16 + lm;
#pragma unroll
    for (int r = 0; r < 4; ++r) {
      const int row = qr0 + quad * 4 + r;
      float v = sc[g][r] * 0.125f;
      v = (col > row || v == 0.0f) ? -INFINITY : v;
      sc[g][r] = v;
      rm[r] = fmaxf(rm[r], v);
    }
  }
  float m_i[4], l_i[4];
#pragma unroll
  for (int r = 0; r < 4; ++r) {
    for (int off = 1; off < 16; off <<= 1) rm[r] = fmaxf(rm[r], __shfl_xor(rm[r], off, 16));
    m_i[r] = rm[r];
  }
  float rs[4] = {0.f, 0.f, 0.f, 0.f};
#pragma unroll
  for (int g = 0; g < 8; ++g)
#pragma unroll
    for (int r = 0; r < 4; ++r) {
      float p = (sc[g][r] == -INFINITY) ? 0.f : __expf(sc[g][r] - m_i[r]);
      sc[g][r] = p;
      rs[r] += p;
    }
#pragma unroll
  for (int r = 0; r < 4; ++r) {
    for (int off = 1; off < 16; off <<= 1) rs[r] += __shfl_xor(rs[r], off, 16);
    l_i[r] = rs[r];
  }

  // P -> LDS (C layout -> A-operand layout), per-wave private, no barrier
#pragma unroll
  for (int g = 0; g < 8; ++g)
#pragma unroll
    for (int r = 0; r < 4; ++r)
      Plds[w][quad * 4 + r][g * 16 + lm] = f2bf(sc[g][r]);

  // O = P V over 128 keys (4 kc2 chunks of 32)
  f32x4 o[4] = {{0.f,0.f,0.f,0.f},{0.f,0.f,0.f,0.f},{0.f,0.f,0.f,0.f},{0.f,0.f,0.f,0.f}};
#pragma unroll
  for (int kc2 = 0; kc2 < 2; ++kc2) {
    bf16x8 pf = *(const bf16x8*)&Plds[w][lm][kc2 * 32 + quad * 8];
#pragma unroll
    for (int nt = 0; nt < 4; ++nt)
      o[nt] = __builtin_amdgcn_mfma_f32_16x16x32_bf16(pf, vfA[kc2][nt], o[nt], 0, 0, 0);
  }
#pragma unroll
  for (int kc2 = 2; kc2 < 4; ++kc2) {
    bf16x8 pf = *(const bf16x8*)&Plds[w][lm][kc2 * 32 + quad * 8];
#pragma unroll
    for (int nt = 0; nt < 4; ++nt) {
      bf16x8 vf = *(const bf16x8*)(KThi + ((size_t)b * AH + nt * 16 + lm) * SLEN +
                                   k0 + kc2 * 32 + quad * 8);
      o[nt] = __builtin_amdgcn_mfma_f32_16x16x32_bf16(pf, vf, o[nt], 0, 0, 0);
    }
  }

  // write partials: bf16 O (contiguous 8 KB/block) + packed (m,l)
  const int slot = b * 272 + slot_off(qt) + chunk;
  short* Ob = OpartH + (size_t)slot * 4096;
#pragma unroll
  for (int nt = 0; nt < 4; ++nt)
#pragma unroll
    for (int r = 0; r < 4; ++r)
      Ob[(size_t)(w * 16 + quad * 4 + r) * AH + nt * 16 + lm] = f2bf(o[nt][r]);
  if (lm == 0) {
#pragma unroll
    for (int r = 0; r < 4; ++r)
      mlpart[(size_t)slot * 64 + w * 16 + quad * 4 + r] = make_float2(m_i[r], l_i[r]);
  }
}

// ---------------------------------------------------------------------------
// Kernel 3: merge, one wave per output row (8192 waves). <=16 chunks/row.
// Lane c=l&15 loads (m,l); weights broadcast via shuffle; 4 accumulators.
// ---------------------------------------------------------------------------
__global__ __launch_bounds__(256) void merge_kernel(const short* __restrict__ OpartH,
                                                    const float2* __restrict__ mlpart,
                                                    float* __restrict__ out) {
  const int t = threadIdx.x, w = t >> 6, l = t & 63;
  const int row = blockIdx.x * 4 + w;
  const int b = row >> 11, s = row & 2047, qt = s >> 6, r = s & 63;
  const int nch = (qt >> 1) + 1;
  const int slotbase = b * 272 + slot_off(qt);

  const int c16 = l & 15;
  float mc = -INFINITY, lc = 0.f;
  if (c16 < nch) {
    float2 ml = mlpart[(size_t)(slotbase + c16) * 64 + r];
    mc = ml.x; lc = ml.y;
  }
  float M = mc;
  for (int off = 1; off < 16; off <<= 1) M = fmaxf(M, __shfl_xor(M, off, 16));
  float wgt = (mc != -INFINITY) ? __expf(mc - M) : 0.f;
  float lw = lc * wgt;
  float L = lw;
  for (int off = 1; off < 16; off <<= 1) L += __shfl_xor(L, off, 16);

  const size_t obase = (size_t)slotbase * 4096 + (size_t)r * AH + l;
  float a0 = 0.f, a1 = 0.f, a2 = 0.f, a3 = 0.f;
  int c = 0;
  for (; c + 3 < nch; c += 4) {
    a0 += __shfl(wgt, c)     * bf2f(OpartH[obase + (size_t)c * 4096]);
    a1 += __shfl(wgt, c + 1) * bf2f(OpartH[obase + (size_t)(c + 1) * 4096]);
    a2 += __shfl(wgt, c + 2) * bf2f(OpartH[obase + (size_t)(c + 2) * 4096]);
    a3 += __shfl(wgt, c + 3) * bf2f(OpartH[obase + (size_t)(c + 3) * 4096]);
  }
  for (; c < nch; ++c) a0 += __shfl(wgt, c) * bf2f(OpartH[obase + (size_t)c * 4096]);
  float acc = (a0 + a1) + (a2 + a3);
  out[(size_t)row * AH + l] = acc / L;
}

// ---------------------------------------------------------------------------
// Workspace (bytes):
//   Bpk     [0,        262144)
//   Khi     [262144,   1310720)
//   Klo     [1310720,  2359296)
//   KThi    [2359296,  3407872)
//   OpartH  [3407872,  12320768)   1088 slots x 4096 bf16 (8.9 MB)
//   mlpart  [12320768, 12877824)   1088 x 64 float2
// ---------------------------------------------------------------------------
extern "C" void kernel_launch(void* const* d_in, const int* in_sizes, int n_in,
                              void* d_out, int out_size, void* d_ws, size_t ws_size,
                              hipStream_t stream) {
  const float* emb = (const float*)d_in[0];
  const float* Wk  = (const float*)d_in[1];
  float* out = (float*)d_out;
  char* ws = (char*)d_ws;

  short*  Bpk    = (short*)(ws);
  short*  Khi    = (short*)(ws + 262144);
  short*  Klo    = (short*)(ws + 1310720);
  short*  KThi   = (short*)(ws + 2359296);
  short*  OpartH = (short*)(ws + 3407872);
  float2* mlpart = (float2*)(ws + 12320768);

  prep_wk_kernel<<<dim3(32), dim3(256), 0, stream>>>(Wk, Bpk);
  gemm_k_kernel<<<dim3(512), dim3(256), 0, stream>>>(emb, Bpk, Khi, Klo, KThi);
  flash_kernel<<<dim3(16, 32, 4), dim3(256), 0, stream>>>(Khi, Klo, KThi, OpartH, mlpart);
  merge_kernel<<<dim3(2048), dim3(256), 0, stream>>>(OpartH, mlpart, out);
}